// Round 9
// baseline (259.267 us; speedup 1.0000x reference)
//
#include <hip/hip_runtime.h>
#include <hip/hip_bf16.h>

typedef __attribute__((ext_vector_type(8))) __bf16   bf16x8;
typedef __attribute__((ext_vector_type(4))) _Float16 f16x4;
typedef __attribute__((ext_vector_type(8))) _Float16 f16x8;
typedef __attribute__((ext_vector_type(4))) float    f32x4;
typedef __attribute__((ext_vector_type(4))) int      i32x4;
typedef __attribute__((ext_vector_type(8))) unsigned short u16x8;

namespace {
constexpr int kB   = 16;
constexpr int kSQ  = 2048;
constexpr int kSK  = 2048;
constexpr int kD   = 64;
constexpr int kQB  = 16;      // q-rows per workgroup
constexpr int kNW  = 4;       // waves per workgroup (256 threads)
constexpr int kTPW = 32;      // 16-key tiles per wave (512 keys/wave)
constexpr int kNT  = kSK / 16;            // 128 tiles per batch-row
constexpr int kCStride = 68;
constexpr int kStgStride = 144;           // bounce row stride (bytes)
constexpr float kScaleLog2e = 0.18033688011112042f; // (1/8)*log2(e)
// ws layout: Kp bf16 frags (4 MB) | Vp f16 frags (4 MB)
constexpr size_t kVpOff = 4u << 20;
}

// ---- setup 1: K[b][key][d] f32 -> Kp fragment-ordered bf16 ----
__global__ __launch_bounds__(256)
void conv_k(const float* __restrict__ K, unsigned short* __restrict__ Kp)
{
  const int idx = blockIdx.x * 256 + threadIdx.x;  // 262144
  const int lam = idx & 63, f = (idx >> 6) & 1, kt = (idx >> 7) & (kNT - 1),
            b = idx >> 14;
  const int l15 = lam & 15, kg = lam >> 4;
  const float* src = K + ((size_t)(b * kSK + kt * 16 + l15) * kD) + f * 32 + kg * 8;
  u16x8 o;
#pragma unroll
  for (int e = 0; e < 8; ++e) {
    union { float f; unsigned int u; } cv; cv.f = src[e];
    unsigned int r = cv.u + 0x7fff + ((cv.u >> 16) & 1);  // RNE bf16
    o[e] = (unsigned short)(r >> 16);
  }
  *reinterpret_cast<u16x8*>(Kp + (size_t)idx * 8) = o;
}

// ---- setup 2: V -> Vp f16, dblk-pair packed (2 dwordx4 per tile-lane) ----
__global__ __launch_bounds__(256)
void conv_v(const float* __restrict__ V, _Float16* __restrict__ Vp)
{
  const int idx = blockIdx.x * 256 + threadIdx.x;  // 262144
  const int h = idx & 1, lam = (idx >> 1) & 63, t = (idx >> 7) & (kNT - 1),
            b = idx >> 14;
  const int l15 = lam & 15, kg = lam >> 4;
  f16x8 o;
#pragma unroll
  for (int j = 0; j < 2; ++j)
#pragma unroll
    for (int e = 0; e < 4; ++e)
      o[j * 4 + e] = (_Float16)
          V[((size_t)(b * kSK + t * 16 + kg * 4 + e) * kD) + (2 * h + j) * 16 + l15];
  *reinterpret_cast<f16x8*>(Vp + (size_t)idx * 8) = o;
}

// ---- main: fused mask-compress + register-resident-P attention ----
// P0: wg ballot-compresses its 16 mask rows (128 KB int32, coalesced
//     streaming) into a 4 KB LDS bit table; overlaps with other wgs' P2
//     write bursts on the same CU.
// P1: swapped QK^T (mfma(K,Q)) + LDS bits + exp2 -> f16 P in VGPRs.
// P2: attn stores via per-wave LDS bounce, full 128B lines.
// P3: PV via 16x16x16 f16 (P is the B operand verbatim), V prefetch.
// P4: cross-wave ctx reduce + store.
__global__ __launch_bounds__(256, 4)
void sdpa_main(const float* __restrict__ Qg, const unsigned short* __restrict__ Kp,
               const _Float16* __restrict__ Vp, const int* __restrict__ Mg,
               float* __restrict__ ctxOut, float* __restrict__ attnOut)
{
  __shared__ float sums[kNW][kQB];
  __shared__ __align__(16) float cpart[kNW][kQB][kCStride];
  __shared__ __align__(16) char stg[kNW * kQB * kStgStride];     // 9216 B
  __shared__ __align__(16) unsigned long long bitsLds[kQB][34];  // 4352 B

  const int tid  = threadIdx.x;
  const int wid  = tid >> 6;           // 0..3
  const int lane = tid & 63;
  const int l15  = lane & 15;
  const int kg   = lane >> 4;

  // XCD-bijective swizzle: 2048 wgs = 8 XCDs x 256 contiguous (2 batches/XCD).
  const int wg = (blockIdx.x & 7) * 256 + (blockIdx.x >> 3);
  const int b  = wg >> 7;
  const int q0 = (wg & 127) * kQB;

  const float* Qb = Qg + (size_t)b * kSQ * kD;
  const int qrow  = q0 + l15;
  const int kbase = wid * (kTPW * 16);
  const int gt0   = wid * kTPW;

  const unsigned short* Kpb = Kp + (size_t)b * kNT * 2 * 64 * 8;
  const _Float16*       Vpb = Vp + (size_t)b * kNT * 64 * 16;

  // Q fragment (B operand of swapped QK^T): col=l15=q, k=kg*8+e.
  bf16x8 qf0, qf1;
  {
    const float* qp = Qb + (size_t)qrow * kD + kg * 8;
#pragma unroll
    for (int e = 0; e < 8; ++e) { qf0[e] = (__bf16)qp[e]; qf1[e] = (__bf16)qp[32 + e]; }
  }

  // ---- P0: ballot-compress this wg's 16 mask rows into LDS bits ----
  // Wave wid owns local rows wid*4..+3. Pass p covers rows {p*2, p*2+1}:
  // iter i: read M[q0+rl][w*64+lane] (256B coalesced), ballot -> u64 whose
  // bit `lane` = key w*64+lane; lane i keeps word of iter i; one bulk write.
  {
    const int* mbase = Mg + (size_t)b * kSQ * kSK;
#pragma unroll
    for (int p = 0; p < 2; ++p) {
      unsigned long long myword = 0;
#pragma unroll
      for (int i = 0; i < 64; ++i) {
        const int rl = wid * 4 + p * 2 + (i >> 5);
        const int v  = mbase[(size_t)(q0 + rl) * kSK + (i & 31) * 64 + lane];
        const unsigned long long bb = __ballot(v != 0);
        if (lane == i) myword = bb;
      }
      bitsLds[wid * 4 + p * 2 + (lane >> 5)][lane & 31] = myword;
    }
  }
  __syncthreads();

  // mask bits for this lane's row & this wave's 512 keys: 16 u32 from LDS
  unsigned int mw[16];
  {
    const unsigned int* rowbits =
        reinterpret_cast<const unsigned int*>(&bitsLds[l15][0]) + wid * 16;
#pragma unroll
    for (int i = 0; i < 4; ++i) {
      const i32x4 v = *reinterpret_cast<const i32x4*>(rowbits + i * 4);
#pragma unroll
      for (int j = 0; j < 4; ++j) mw[i * 4 + j] = (unsigned int)v[j];
    }
  }

  auto kfrag = [&](int t, int f) {
    return *reinterpret_cast<const bf16x8*>(
        Kpb + (((size_t)(gt0 + t) * 2 + f) * 64 + lane) * 8);
  };

  // ---- P1: QK^T + bitmask + exp -> packed f16 P in registers ----
  f16x4 pb[kTPW];
  float lsum = 0.f;
  bf16x8 kb0[2], kb1[2];
  kb0[0] = kfrag(0, 0); kb1[0] = kfrag(0, 1);
#pragma unroll
  for (int t = 0; t < kTPW; ++t) {
    const int cur = t & 1, nxt = cur ^ 1;
    if (t + 1 < kTPW) { kb0[nxt] = kfrag(t + 1, 0); kb1[nxt] = kfrag(t + 1, 1); }
    f32x4 acc = {0.f, 0.f, 0.f, 0.f};
    acc = __builtin_amdgcn_mfma_f32_16x16x32_bf16(kb0[cur], qf0, acc, 0, 0, 0);
    acc = __builtin_amdgcn_mfma_f32_16x16x32_bf16(kb1[cur], qf1, acc, 0, 0, 0);
    const unsigned int bits4 =
        (mw[t >> 1] >> (((t & 1) << 4) + (kg << 2))) & 15u;
    f16x4 p4;
#pragma unroll
    for (int r = 0; r < 4; ++r) {
      const float pv = ((bits4 >> r) & 1u)
                           ? 0.f
                           : __builtin_amdgcn_exp2f(acc[r] * kScaleLog2e);
      lsum += pv;
      p4[r] = (_Float16)pv;
    }
    pb[t] = p4;
  }
  lsum += __shfl_xor(lsum, 16, 64);
  lsum += __shfl_xor(lsum, 32, 64);
  if (lane < 16) sums[wid][l15] = lsum;
  __syncthreads();

  // ---- P2: attn stores via per-wave bounce; full 128B line per instr ----
  {
    const int r0 = lane >> 3, r1 = r0 + 8;
    float la = 0.f, lb = 0.f;
#pragma unroll
    for (int w = 0; w < kNW; ++w) { la += sums[w][r0]; lb += sums[w][r1]; }
    const float invA = 1.0f / la, invB = 1.0f / lb;
    char* sw = stg + wid * (kQB * kStgStride);
    const int c8 = (lane & 7) * 8;      // byte col of this lane's f16x4
    float* arow0 = attnOut + ((size_t)b * kSQ + q0 + r0) * kSK + kbase;
    float* arow1 = attnOut + ((size_t)b * kSQ + q0 + r1) * kSK + kbase;
#pragma unroll
    for (int g = 0; g < 8; ++g) {       // 4 tiles (64 cols) per group
#pragma unroll
      for (int tl = 0; tl < 4; ++tl)
        *reinterpret_cast<f16x4*>(sw + l15 * kStgStride + tl * 32 + kg * 8)
            = pb[g * 4 + tl];
      const f16x4 x0a = *reinterpret_cast<const f16x4*>(sw + r0 * kStgStride + c8);
      const f16x4 x0b = *reinterpret_cast<const f16x4*>(sw + r0 * kStgStride + 64 + c8);
      const f16x4 x1a = *reinterpret_cast<const f16x4*>(sw + r1 * kStgStride + c8);
      const f16x4 x1b = *reinterpret_cast<const f16x4*>(sw + r1 * kStgStride + 64 + c8);
      float4 o;
      const int cA = g * 64 + (lane & 7) * 4;   // lanes 0..7 -> one full line
      o.x = (float)x0a[0] * invA; o.y = (float)x0a[1] * invA;
      o.z = (float)x0a[2] * invA; o.w = (float)x0a[3] * invA;
      *reinterpret_cast<float4*>(arow0 + cA) = o;
      o.x = (float)x0b[0] * invA; o.y = (float)x0b[1] * invA;
      o.z = (float)x0b[2] * invA; o.w = (float)x0b[3] * invA;
      *reinterpret_cast<float4*>(arow0 + cA + 32) = o;
      o.x = (float)x1a[0] * invB; o.y = (float)x1a[1] * invB;
      o.z = (float)x1a[2] * invB; o.w = (float)x1a[3] * invB;
      *reinterpret_cast<float4*>(arow1 + cA) = o;
      o.x = (float)x1b[0] * invB; o.y = (float)x1b[1] * invB;
      o.z = (float)x1b[2] * invB; o.w = (float)x1b[3] * invB;
      *reinterpret_cast<float4*>(arow1 + cA + 32) = o;
    }
  }

  // ---- P3: PV via 16x16x16 f16 (V prefetched 1 tile ahead) ----
  f32x4 cacc[4];
#pragma unroll
  for (int d = 0; d < 4; ++d) cacc[d] = f32x4{0.f, 0.f, 0.f, 0.f};
  f16x8 v01[2], v23[2];
  {
    const _Float16* vb = Vpb + ((size_t)gt0 * 64 + lane) * 16;
    v01[0] = *reinterpret_cast<const f16x8*>(vb);
    v23[0] = *reinterpret_cast<const f16x8*>(vb + 8);
  }
#pragma unroll
  for (int t = 0; t < kTPW; ++t) {
    const int cur = t & 1, nxt = cur ^ 1;
    if (t + 1 < kTPW) {
      const _Float16* vb = Vpb + ((size_t)(gt0 + t + 1) * 64 + lane) * 16;
      v01[nxt] = *reinterpret_cast<const f16x8*>(vb);
      v23[nxt] = *reinterpret_cast<const f16x8*>(vb + 8);
    }
    const f16x4 pfrag = pb[t];
    union { f16x8 v; f16x4 h[2]; } a, c;
    a.v = v01[cur]; c.v = v23[cur];
    cacc[0] = __builtin_amdgcn_mfma_f32_16x16x16f16(a.h[0], pfrag, cacc[0], 0, 0, 0);
    cacc[1] = __builtin_amdgcn_mfma_f32_16x16x16f16(a.h[1], pfrag, cacc[1], 0, 0, 0);
    cacc[2] = __builtin_amdgcn_mfma_f32_16x16x16f16(c.h[0], pfrag, cacc[2], 0, 0, 0);
    cacc[3] = __builtin_amdgcn_mfma_f32_16x16x16f16(c.h[1], pfrag, cacc[3], 0, 0, 0);
  }
#pragma unroll
  for (int dblk = 0; dblk < 4; ++dblk)
    *reinterpret_cast<f32x4*>(&cpart[wid][l15][dblk * 16 + kg * 4]) = cacc[dblk];
  __syncthreads();

  // ---- P4: cross-wave reduce + scale + ctx store ----
  {
    const int q = tid >> 4;
    const int d = (tid & 15) * 4;
    float4 o = make_float4(0.f, 0.f, 0.f, 0.f);
#pragma unroll
    for (int w = 0; w < kNW; ++w) {
      const float4 p = *reinterpret_cast<const float4*>(&cpart[w][q][d]);
      o.x += p.x; o.y += p.y; o.z += p.z; o.w += p.w;
    }
    float l = 0.f;
#pragma unroll
    for (int w = 0; w < kNW; ++w) l += sums[w][q];
    const float iv = 1.0f / l;
    o.x *= iv; o.y *= iv; o.z *= iv; o.w *= iv;
    *reinterpret_cast<float4*>(ctxOut + ((size_t)b * kSQ + q0 + q) * kD + d) = o;
  }
}

extern "C" void kernel_launch(void* const* d_in, const int* in_sizes, int n_in,
                              void* d_out, int out_size, void* d_ws, size_t ws_size,
                              hipStream_t stream)
{
  const float* Q = (const float*)d_in[0];
  const float* K = (const float*)d_in[1];
  const float* V = (const float*)d_in[2];
  const int*   M = (const int*)d_in[3];   // bool mask pushed as 4-byte words
  float* ctx  = (float*)d_out;
  float* attn = (float*)d_out + (size_t)kB * kSQ * kD;

  unsigned short* Kp = (unsigned short*)d_ws;
  _Float16*       Vp = (_Float16*)((char*)d_ws + kVpOff);

  hipLaunchKernelGGL(conv_k, dim3(1024), dim3(256), 0, stream, K, Kp);
  hipLaunchKernelGGL(conv_v, dim3(1024), dim3(256), 0, stream, V, Vp);
  hipLaunchKernelGGL(sdpa_main, dim3(kB * kSQ / kQB), dim3(256), 0, stream,
                     Q, Kp, Vp, M, ctx, attn);
}